// Round 11
// baseline (80.572 us; speedup 1.0000x reference)
//
#include <hip/hip_runtime.h>
#include <math.h>

#define Bb 128
#define Ee 256
#define Mm 64
#define Cc 5
#define NTOT (Bb*Mm*Ee)   // 2097152
#define BE  (Bb*Ee)       // 32768
#define EPS 1e-5f
#define L2E2 2.8853900817779268f   // 2*log2(e)

#if __has_builtin(__builtin_amdgcn_exp2f)
#define EXP2(x) __builtin_amdgcn_exp2f(x)
#else
#define EXP2(x) exp2f(x)
#endif
#define RCP(x) __builtin_amdgcn_rcpf(x)

// native clang vector (ext_vector_type) -- accepted by nontemporal builtins
typedef float vfloat4 __attribute__((ext_vector_type(4)));

// Non-temporal float4 load: inputs are single-use per launch; NT avoids
// LLC insertion churn (the A/B this round is testing).
__device__ __forceinline__ vfloat4 ldnt(const float* p) {
    return __builtin_nontemporal_load((const vfloat4*)p);
}

// tanh with pre-scaled (by 2*log2e) weights: 1 - 2/(2^(x*w+b+h*u)+1).
__device__ __forceinline__ float tanh_step(float x, float w, float b, float u, float h) {
    float t = __builtin_fmaf(x, w, b);
    t = __builtin_fmaf(h, u, t);
    float r = RCP(EXP2(t) + 1.0f);
    return __builtin_fmaf(-2.0f, r, 1.0f);
}

__device__ __forceinline__ unsigned short f32_to_bf16_rne(float f) {
    unsigned u = __float_as_uint(f);
    unsigned r = (u + 0x7fffu + ((u >> 16) & 1u)) >> 16;
    return (unsigned short)r;
}
__device__ __forceinline__ float bf16_to_f32(unsigned short s) {
    return __uint_as_float(((unsigned)s) << 16);
}

// ---------------------------------------------------------------------------
// Kernel 1: per-sample scalar RNNs over T=4/8/16 + 1x3 conv fusion.
// Round-5 structure; ONLY change: non-temporal input loads (LLC-policy A/B).
// Block 0 re-zeroes the stats scratch each call (stream-ordered).
// fusion stored bf16 [m][b*E+e] so k_rnn2's per-step loads are coalesced.
// ---------------------------------------------------------------------------
__global__ __launch_bounds__(256, 8) void k_rnn1(
    const float* __restrict__ a0, const float* __restrict__ a1,
    const float* __restrict__ a2,
    const float* __restrict__ wih, const float* __restrict__ whh,
    const float* __restrict__ bih, const float* __restrict__ bhh,
    const float* __restrict__ cw,  const float* __restrict__ cb,
    unsigned short* __restrict__ fusion,
    float* __restrict__ stats)
{
    int t = blockIdx.x * blockDim.x + threadIdx.x;

    if (blockIdx.x == 0) {
        stats[threadIdx.x]       = 0.0f;   // sum[e]
        stats[256 + threadIdx.x] = 0.0f;   // sumsq[e]
    }

    float w0 = wih[0] * L2E2, w1 = wih[1] * L2E2, w2 = wih[2] * L2E2;
    float u0 = whh[0] * L2E2, u1 = whh[1] * L2E2, u2 = whh[2] * L2E2;
    float b0 = (bih[0] + bhh[0]) * L2E2;
    float b1 = (bih[1] + bhh[1]) * L2E2;
    float b2 = (bih[2] + bhh[2]) * L2E2;
    float c0 = cw[0], c1 = cw[1], c2 = cw[2], cbias = cb[0];

    #pragma unroll
    for (int s = 0; s < 2; ++s) {
        int n = t + s * (NTOT / 2);

        // scale 0: T=4
        vfloat4 x0 = ldnt(a0 + 4*(size_t)n);
        float h0 = tanh_step(x0.x, w0, b0, u0, 0.0f);
        h0 = tanh_step(x0.y, w0, b0, u0, h0);
        h0 = tanh_step(x0.z, w0, b0, u0, h0);
        h0 = tanh_step(x0.w, w0, b0, u0, h0);

        // scale 1: T=8
        vfloat4 y0 = ldnt(a1 + 8*(size_t)n);
        vfloat4 y1 = ldnt(a1 + 8*(size_t)n + 4);
        float h1 = tanh_step(y0.x, w1, b1, u1, 0.0f);
        h1 = tanh_step(y0.y, w1, b1, u1, h1);
        h1 = tanh_step(y0.z, w1, b1, u1, h1);
        h1 = tanh_step(y0.w, w1, b1, u1, h1);
        h1 = tanh_step(y1.x, w1, b1, u1, h1);
        h1 = tanh_step(y1.y, w1, b1, u1, h1);
        h1 = tanh_step(y1.z, w1, b1, u1, h1);
        h1 = tanh_step(y1.w, w1, b1, u1, h1);

        // scale 2: T=16
        float h2 = 0.0f;
        #pragma unroll
        for (int q = 0; q < 4; ++q) {
            vfloat4 z = ldnt(a2 + 16*(size_t)n + 4*q);
            h2 = tanh_step(z.x, w2, b2, u2, h2);
            h2 = tanh_step(z.y, w2, b2, u2, h2);
            h2 = tanh_step(z.z, w2, b2, u2, h2);
            h2 = tanh_step(z.w, w2, b2, u2, h2);
        }

        float f = h0 * c0 + h1 * c1 + h2 * c2 + cbias;

        int e = n & (Ee - 1);
        int m = (n >> 8) & (Mm - 1);
        int b = n >> 14;
        fusion[(m << 15) + (b << 8) + e] = f32_to_bf16_rne(f);
    }
}

// ---------------------------------------------------------------------------
// Kernel 2: second scalar RNN over m for each (b,e) lane (bf16 input),
// PLUS per-channel BN statistics contribution via device-scope atomicAdd.
// Ordering/visibility for the consumer comes from the KERNEL BOUNDARY.
// block = batch row b, thread = channel e.
// ---------------------------------------------------------------------------
__global__ __launch_bounds__(256) void k_rnn2(
    const unsigned short* __restrict__ fusion,
    const float* __restrict__ w, const float* __restrict__ u,
    const float* __restrict__ bi, const float* __restrict__ bh,
    float* __restrict__ feat, float* __restrict__ stats)
{
    const int e = threadIdx.x;
    const int j = (blockIdx.x << 8) + e;

    float wv = w[0] * L2E2, uv = u[0] * L2E2, bb = (bi[0] + bh[0]) * L2E2;
    float h = 0.0f;
    #pragma unroll 16
    for (int m = 0; m < Mm; ++m) {
        float x = bf16_to_f32(fusion[m * BE + j]);
        h = tanh_step(x, wv, bb, uv, h);
    }
    feat[j] = h;
    atomicAdd(&stats[e], h);
    atomicAdd(&stats[256 + e], h * h);
}

// ---------------------------------------------------------------------------
// Kernel 3: BN (stats precomputed) + ReLU + (E->C) linear + softmax.
// One block per batch row; no stats loop -- reads stats[] directly.
// ---------------------------------------------------------------------------
__global__ __launch_bounds__(256) void k_head(
    const float* __restrict__ feat, const float* __restrict__ stats,
    const float* __restrict__ gamma, const float* __restrict__ beta,
    const float* __restrict__ fw, const float* __restrict__ fb,
    float* __restrict__ out)
{
    int b = blockIdx.x;
    int e = threadIdx.x;

    float s  = stats[e];
    float s2 = stats[256 + e];
    float mean = s * (1.0f / Bb);
    float var  = s2 * (1.0f / Bb) - mean * mean;
    float a = gamma[e] * rsqrtf(var + EPS);
    float shift = beta[e] - mean * a;

    float v = fmaxf(feat[(b << 8) + e] * a + shift, 0.0f);

    float p[Cc];
    #pragma unroll
    for (int c = 0; c < Cc; ++c) p[c] = v * fw[c * Ee + e];

    #pragma unroll
    for (int off = 32; off > 0; off >>= 1) {
        #pragma unroll
        for (int c = 0; c < Cc; ++c) p[c] += __shfl_down(p[c], off);
    }

    __shared__ float lds[4][Cc];
    int wave = e >> 6, lane = e & 63;
    if (lane == 0) {
        #pragma unroll
        for (int c = 0; c < Cc; ++c) lds[wave][c] = p[c];
    }
    __syncthreads();

    if (e == 0) {
        float lg[Cc];
        #pragma unroll
        for (int c = 0; c < Cc; ++c)
            lg[c] = lds[0][c] + lds[1][c] + lds[2][c] + lds[3][c] + fb[c];
        float mx = lg[0];
        #pragma unroll
        for (int c = 1; c < Cc; ++c) mx = fmaxf(mx, lg[c]);
        float se = 0.0f;
        #pragma unroll
        for (int c = 0; c < Cc; ++c) { lg[c] = EXP2((lg[c] - mx) * 1.4426950408889634f); se += lg[c]; }
        float inv = RCP(se);
        #pragma unroll
        for (int c = 0; c < Cc; ++c) out[b * Cc + c] = lg[c] * inv;
    }
}

extern "C" void kernel_launch(void* const* d_in, const int* in_sizes, int n_in,
                              void* d_out, int out_size, void* d_ws, size_t ws_size,
                              hipStream_t stream) {
    const float* a0       = (const float*)d_in[0];
    const float* a1       = (const float*)d_in[1];
    const float* a2       = (const float*)d_in[2];
    const float* rnn1_wih = (const float*)d_in[3];
    const float* rnn1_whh = (const float*)d_in[4];
    const float* rnn1_bih = (const float*)d_in[5];
    const float* rnn1_bhh = (const float*)d_in[6];
    const float* conv_w   = (const float*)d_in[7];
    const float* conv_b   = (const float*)d_in[8];
    const float* rnn2_wih = (const float*)d_in[9];
    const float* rnn2_whh = (const float*)d_in[10];
    const float* rnn2_bih = (const float*)d_in[11];
    const float* rnn2_bhh = (const float*)d_in[12];
    const float* gamma    = (const float*)d_in[13];
    const float* beta     = (const float*)d_in[14];
    const float* fnn_w    = (const float*)d_in[15];
    const float* fnn_b    = (const float*)d_in[16];

    float* out = (float*)d_out;

    // workspace layout
    char* ws = (char*)d_ws;
    unsigned short* fusion = (unsigned short*)ws;              // M*BE bf16 = 4 MB
    float* stats = (float*)(ws + (size_t)Mm * BE * 2);         // 512 floats
    float* feat  = stats + 512;                                // BE floats

    k_rnn1<<<NTOT / 2 / 256, 256, 0, stream>>>(a0, a1, a2,
        rnn1_wih, rnn1_whh, rnn1_bih, rnn1_bhh, conv_w, conv_b,
        fusion, stats);
    k_rnn2<<<Bb, 256, 0, stream>>>(fusion,
        rnn2_wih, rnn2_whh, rnn2_bih, rnn2_bhh, feat, stats);
    k_head<<<Bb, 256, 0, stream>>>(feat, stats,
        gamma, beta, fnn_w, fnn_b, out);
}

// Round 12
// 48.521 us; speedup vs baseline: 1.6605x; 1.6605x over previous
//
#include <hip/hip_runtime.h>
#include <math.h>

#define Bb 128
#define Ee 256
#define Mm 64
#define Cc 5
#define NTOT (Bb*Mm*Ee)   // 2097152
#define BE  (Bb*Ee)       // 32768
#define EPS 1e-5f
#define L2E2 2.8853900817779268f   // 2*log2(e)

#if __has_builtin(__builtin_amdgcn_exp2f)
#define EXP2(x) __builtin_amdgcn_exp2f(x)
#else
#define EXP2(x) exp2f(x)
#endif
#define RCP(x) __builtin_amdgcn_rcpf(x)

// tanh with pre-scaled (by 2*log2e) weights: 1 - 2/(2^(x*w+b+h*u)+1).
__device__ __forceinline__ float tanh_step(float x, float w, float b, float u, float h) {
    float t = __builtin_fmaf(x, w, b);
    t = __builtin_fmaf(h, u, t);
    float r = RCP(EXP2(t) + 1.0f);
    return __builtin_fmaf(-2.0f, r, 1.0f);
}

__device__ __forceinline__ unsigned short f32_to_bf16_rne(float f) {
    unsigned u = __float_as_uint(f);
    unsigned r = (u + 0x7fffu + ((u >> 16) & 1u)) >> 16;
    return (unsigned short)r;
}
__device__ __forceinline__ float bf16_to_f32(unsigned short s) {
    return __uint_as_float(((unsigned)s) << 16);
}

// ---------------------------------------------------------------------------
// Kernel 1: per-sample scalar RNNs over T=4/8/16 + 1x3 conv fusion.
// Round-5 structure, DEFAULT cached loads (NT A/B in round 11 regressed 68%:
// the LLC serving ~120MB/launch was load-bearing). At the memory-service
// wall: 235MB single-use input at ~5.5 TB/s effective (~88% of copy ceiling).
// Block 0 re-zeroes the stats scratch each call (stream-ordered).
// fusion stored bf16 [m][b*E+e] so k_rnn2's per-step loads are coalesced.
// ---------------------------------------------------------------------------
__global__ __launch_bounds__(256, 8) void k_rnn1(
    const float* __restrict__ a0, const float* __restrict__ a1,
    const float* __restrict__ a2,
    const float* __restrict__ wih, const float* __restrict__ whh,
    const float* __restrict__ bih, const float* __restrict__ bhh,
    const float* __restrict__ cw,  const float* __restrict__ cb,
    unsigned short* __restrict__ fusion,
    float* __restrict__ stats)
{
    int t = blockIdx.x * blockDim.x + threadIdx.x;

    if (blockIdx.x == 0) {
        stats[threadIdx.x]       = 0.0f;   // sum[e]
        stats[256 + threadIdx.x] = 0.0f;   // sumsq[e]
    }

    float w0 = wih[0] * L2E2, w1 = wih[1] * L2E2, w2 = wih[2] * L2E2;
    float u0 = whh[0] * L2E2, u1 = whh[1] * L2E2, u2 = whh[2] * L2E2;
    float b0 = (bih[0] + bhh[0]) * L2E2;
    float b1 = (bih[1] + bhh[1]) * L2E2;
    float b2 = (bih[2] + bhh[2]) * L2E2;
    float c0 = cw[0], c1 = cw[1], c2 = cw[2], cbias = cb[0];

    #pragma unroll
    for (int s = 0; s < 2; ++s) {
        int n = t + s * (NTOT / 2);

        // scale 0: T=4
        float4 x0 = ((const float4*)a0)[n];
        float h0 = tanh_step(x0.x, w0, b0, u0, 0.0f);
        h0 = tanh_step(x0.y, w0, b0, u0, h0);
        h0 = tanh_step(x0.z, w0, b0, u0, h0);
        h0 = tanh_step(x0.w, w0, b0, u0, h0);

        // scale 1: T=8
        float4 y0 = ((const float4*)a1)[2*n + 0];
        float4 y1 = ((const float4*)a1)[2*n + 1];
        float h1 = tanh_step(y0.x, w1, b1, u1, 0.0f);
        h1 = tanh_step(y0.y, w1, b1, u1, h1);
        h1 = tanh_step(y0.z, w1, b1, u1, h1);
        h1 = tanh_step(y0.w, w1, b1, u1, h1);
        h1 = tanh_step(y1.x, w1, b1, u1, h1);
        h1 = tanh_step(y1.y, w1, b1, u1, h1);
        h1 = tanh_step(y1.z, w1, b1, u1, h1);
        h1 = tanh_step(y1.w, w1, b1, u1, h1);

        // scale 2: T=16
        float h2 = 0.0f;
        #pragma unroll
        for (int q = 0; q < 4; ++q) {
            float4 z = ((const float4*)a2)[4*n + q];
            h2 = tanh_step(z.x, w2, b2, u2, h2);
            h2 = tanh_step(z.y, w2, b2, u2, h2);
            h2 = tanh_step(z.z, w2, b2, u2, h2);
            h2 = tanh_step(z.w, w2, b2, u2, h2);
        }

        float f = h0 * c0 + h1 * c1 + h2 * c2 + cbias;

        int e = n & (Ee - 1);
        int m = (n >> 8) & (Mm - 1);
        int b = n >> 14;
        fusion[(m << 15) + (b << 8) + e] = f32_to_bf16_rne(f);
    }
}

// ---------------------------------------------------------------------------
// Kernel 2: second scalar RNN over m for each (b,e) lane (bf16 input),
// PLUS per-channel BN statistics contribution via device-scope atomicAdd.
// Ordering/visibility for the consumer comes from the KERNEL BOUNDARY.
// block = batch row b, thread = channel e.
// ---------------------------------------------------------------------------
__global__ __launch_bounds__(256) void k_rnn2(
    const unsigned short* __restrict__ fusion,
    const float* __restrict__ w, const float* __restrict__ u,
    const float* __restrict__ bi, const float* __restrict__ bh,
    float* __restrict__ feat, float* __restrict__ stats)
{
    const int e = threadIdx.x;
    const int j = (blockIdx.x << 8) + e;

    float wv = w[0] * L2E2, uv = u[0] * L2E2, bb = (bi[0] + bh[0]) * L2E2;
    float h = 0.0f;
    #pragma unroll 16
    for (int m = 0; m < Mm; ++m) {
        float x = bf16_to_f32(fusion[m * BE + j]);
        h = tanh_step(x, wv, bb, uv, h);
    }
    feat[j] = h;
    atomicAdd(&stats[e], h);
    atomicAdd(&stats[256 + e], h * h);
}

// ---------------------------------------------------------------------------
// Kernel 3: BN (stats precomputed) + ReLU + (E->C) linear + softmax.
// One block per batch row; no stats loop -- reads stats[] directly.
// ---------------------------------------------------------------------------
__global__ __launch_bounds__(256) void k_head(
    const float* __restrict__ feat, const float* __restrict__ stats,
    const float* __restrict__ gamma, const float* __restrict__ beta,
    const float* __restrict__ fw, const float* __restrict__ fb,
    float* __restrict__ out)
{
    int b = blockIdx.x;
    int e = threadIdx.x;

    float s  = stats[e];
    float s2 = stats[256 + e];
    float mean = s * (1.0f / Bb);
    float var  = s2 * (1.0f / Bb) - mean * mean;
    float a = gamma[e] * rsqrtf(var + EPS);
    float shift = beta[e] - mean * a;

    float v = fmaxf(feat[(b << 8) + e] * a + shift, 0.0f);

    float p[Cc];
    #pragma unroll
    for (int c = 0; c < Cc; ++c) p[c] = v * fw[c * Ee + e];

    #pragma unroll
    for (int off = 32; off > 0; off >>= 1) {
        #pragma unroll
        for (int c = 0; c < Cc; ++c) p[c] += __shfl_down(p[c], off);
    }

    __shared__ float lds[4][Cc];
    int wave = e >> 6, lane = e & 63;
    if (lane == 0) {
        #pragma unroll
        for (int c = 0; c < Cc; ++c) lds[wave][c] = p[c];
    }
    __syncthreads();

    if (e == 0) {
        float lg[Cc];
        #pragma unroll
        for (int c = 0; c < Cc; ++c)
            lg[c] = lds[0][c] + lds[1][c] + lds[2][c] + lds[3][c] + fb[c];
        float mx = lg[0];
        #pragma unroll
        for (int c = 1; c < Cc; ++c) mx = fmaxf(mx, lg[c]);
        float se = 0.0f;
        #pragma unroll
        for (int c = 0; c < Cc; ++c) { lg[c] = EXP2((lg[c] - mx) * 1.4426950408889634f); se += lg[c]; }
        float inv = RCP(se);
        #pragma unroll
        for (int c = 0; c < Cc; ++c) out[b * Cc + c] = lg[c] * inv;
    }
}

extern "C" void kernel_launch(void* const* d_in, const int* in_sizes, int n_in,
                              void* d_out, int out_size, void* d_ws, size_t ws_size,
                              hipStream_t stream) {
    const float* a0       = (const float*)d_in[0];
    const float* a1       = (const float*)d_in[1];
    const float* a2       = (const float*)d_in[2];
    const float* rnn1_wih = (const float*)d_in[3];
    const float* rnn1_whh = (const float*)d_in[4];
    const float* rnn1_bih = (const float*)d_in[5];
    const float* rnn1_bhh = (const float*)d_in[6];
    const float* conv_w   = (const float*)d_in[7];
    const float* conv_b   = (const float*)d_in[8];
    const float* rnn2_wih = (const float*)d_in[9];
    const float* rnn2_whh = (const float*)d_in[10];
    const float* rnn2_bih = (const float*)d_in[11];
    const float* rnn2_bhh = (const float*)d_in[12];
    const float* gamma    = (const float*)d_in[13];
    const float* beta     = (const float*)d_in[14];
    const float* fnn_w    = (const float*)d_in[15];
    const float* fnn_b    = (const float*)d_in[16];

    float* out = (float*)d_out;

    // workspace layout
    char* ws = (char*)d_ws;
    unsigned short* fusion = (unsigned short*)ws;              // M*BE bf16 = 4 MB
    float* stats = (float*)(ws + (size_t)Mm * BE * 2);         // 512 floats
    float* feat  = stats + 512;                                // BE floats

    k_rnn1<<<NTOT / 2 / 256, 256, 0, stream>>>(a0, a1, a2,
        rnn1_wih, rnn1_whh, rnn1_bih, rnn1_bhh, conv_w, conv_b,
        fusion, stats);
    k_rnn2<<<Bb, 256, 0, stream>>>(fusion,
        rnn2_wih, rnn2_whh, rnn2_bih, rnn2_bhh, feat, stats);
    k_head<<<Bb, 256, 0, stream>>>(feat, stats,
        gamma, beta, fnn_w, fnn_b, out);
}